// Round 1
// baseline (5876.157 us; speedup 1.0000x reference)
//
#include <hip/hip_runtime.h>

#define NDIM 512   // D_IN == D_OUT == 512

// ---------------- degree count: deg[row] += 1 ----------------
__global__ __launch_bounds__(256) void deg_kernel(const int* __restrict__ ei,
                                                  float* __restrict__ deg, int E) {
    int e = blockIdx.x * 256 + threadIdx.x;
    if (e < E) atomicAdd(&deg[ei[e]], 1.0f);
}

// ---------------- deg -> deg_inv_sqrt in place ----------------
__global__ __launch_bounds__(256) void rsqrt_kernel(float* __restrict__ deg, int n) {
    int i = blockIdx.x * 256 + threadIdx.x;
    if (i < n) {
        float d = deg[i];
        deg[i] = (d > 0.0f) ? rsqrtf(d) : 0.0f;
    }
}

// ---------------- scatter: agg[col] += x[row] * norm ----------------
// one wave (64 lanes) per edge; lane handles 2 float4 (8 floats)
__global__ __launch_bounds__(256) void scatter_kernel(
        const float* __restrict__ x, const int* __restrict__ ei,
        const float* __restrict__ ea, const float* __restrict__ dis,
        const float* __restrict__ conf_w, const float* __restrict__ conf_b,
        float* __restrict__ agg, int E) {
    int wave = threadIdx.x >> 6;
    int lane = threadIdx.x & 63;
    int e = blockIdx.x * 4 + wave;
    if (e >= E) return;
    int row = ei[e];
    int col = ei[E + e];
    float w = ea[(size_t)e*3+0]*conf_w[0] + ea[(size_t)e*3+1]*conf_w[1]
            + ea[(size_t)e*3+2]*conf_w[2] + conf_b[0];
    w = 1.0f / (1.0f + __expf(-w));               // sigmoid
    float norm = dis[row] * dis[col] * w;          // 0 if col has deg 0 (matches ref)
    const float4* __restrict__ xr = (const float4*)(x + (size_t)row * NDIM);
    float* __restrict__ ar = agg + (size_t)col * NDIM;
#pragma unroll
    for (int j = 0; j < 2; ++j) {
        int idx = j * 64 + lane;                   // contiguous per wave-iteration
        float4 v = xr[idx];
        int b = idx * 4;
        atomicAdd(&ar[b+0], v.x * norm);
        atomicAdd(&ar[b+1], v.y * norm);
        atomicAdd(&ar[b+2], v.z * norm);
        atomicAdd(&ar[b+3], v.w * norm);
    }
}

// ---------------- fp32 GEMM: out[m][n] = sum_k agg[m][k]*W[n][k] + b[n] ----------------
// 64x64 block tile, BK=32, 256 threads, 4x4 micro-tile per thread
#define BM 64
#define BN 64
#define BK 32

__global__ __launch_bounds__(256) void gemm_kernel(
        const float* __restrict__ A,   // [M][512] agg
        const float* __restrict__ W,   // [512][512] row-major [out][in] -> acts as B^T
        const float* __restrict__ bias,
        float* __restrict__ out, int M) {
    __shared__ float As[BK][BM + 4];   // +4 keeps float4 rows 16B-aligned, breaks bank stride
    __shared__ float Bs[BK][BN + 4];
    int m0 = blockIdx.x * BM;
    int n0 = blockIdx.y * BN;
    int tid = threadIdx.x;
    int tx = tid & 15, ty = tid >> 4;
    float acc[4][4] = {};

    for (int k0 = 0; k0 < NDIM; k0 += BK) {
        // stage tiles: 64 rows x 32 cols each = 512 float4s; 2 per thread
#pragma unroll
        for (int i = 0; i < 2; ++i) {
            int idx = tid * 2 + i;          // 0..511
            int r = idx >> 3;               // 0..63
            int c = (idx & 7) * 4;          // 0..28
            float4 v = make_float4(0.f, 0.f, 0.f, 0.f);
            int gm = m0 + r;
            if (gm < M) v = *(const float4*)(A + (size_t)gm * NDIM + k0 + c);
            As[c+0][r] = v.x; As[c+1][r] = v.y; As[c+2][r] = v.z; As[c+3][r] = v.w;
            float4 u = *(const float4*)(W + (size_t)(n0 + r) * NDIM + k0 + c);
            Bs[c+0][r] = u.x; Bs[c+1][r] = u.y; Bs[c+2][r] = u.z; Bs[c+3][r] = u.w;
        }
        __syncthreads();
#pragma unroll
        for (int k = 0; k < BK; ++k) {
            float4 a4 = *(const float4*)&As[k][ty * 4];
            float4 b4 = *(const float4*)&Bs[k][tx * 4];
            float a[4] = {a4.x, a4.y, a4.z, a4.w};
            float b[4] = {b4.x, b4.y, b4.z, b4.w};
#pragma unroll
            for (int i = 0; i < 4; ++i)
#pragma unroll
                for (int j = 0; j < 4; ++j)
                    acc[i][j] += a[i] * b[j];
        }
        __syncthreads();
    }
#pragma unroll
    for (int i = 0; i < 4; ++i) {
        int gm = m0 + ty * 4 + i;
        if (gm >= M) continue;
#pragma unroll
        for (int j = 0; j < 4; ++j) {
            int gn = n0 + tx * 4 + j;
            out[(size_t)gm * NDIM + gn] = acc[i][j] + bias[gn];
        }
    }
}

extern "C" void kernel_launch(void* const* d_in, const int* in_sizes, int n_in,
                              void* d_out, int out_size, void* d_ws, size_t ws_size,
                              hipStream_t stream) {
    const float* x      = (const float*)d_in[0];
    const int*   ei     = (const int*)  d_in[1];   // edge_index [2][E]
    const float* ea     = (const float*)d_in[2];   // edge_attr [E][3]
    const float* lin_w  = (const float*)d_in[3];   // [512][512]
    const float* lin_b  = (const float*)d_in[4];   // [512]
    const float* conf_w = (const float*)d_in[5];   // [3]
    const float* conf_b = (const float*)d_in[6];   // [1]
    float* out = (float*)d_out;

    int N = in_sizes[0] / NDIM;   // 50000
    int E = in_sizes[2] / 3;      // 800000

    // workspace: [deg: N floats][agg: N*512 floats]
    size_t deg_bytes = (size_t)N * sizeof(float);
    size_t agg_off = (deg_bytes + 255) & ~(size_t)255;
    float* deg = (float*)d_ws;
    float* agg = (float*)((char*)d_ws + agg_off);
    size_t zero_bytes = agg_off + (size_t)N * NDIM * sizeof(float);

    hipMemsetAsync(d_ws, 0, zero_bytes, stream);
    deg_kernel<<<(E + 255) / 256, 256, 0, stream>>>(ei, deg, E);
    rsqrt_kernel<<<(N + 255) / 256, 256, 0, stream>>>(deg, N);
    scatter_kernel<<<(E + 3) / 4, 256, 0, stream>>>(x, ei, ea, deg, conf_w, conf_b, agg, E);
    dim3 g((N + BM - 1) / BM, NDIM / BN);
    gemm_kernel<<<g, 256, 0, stream>>>(agg, lin_w, lin_b, out, N);
}

// Round 3
// 987.207 us; speedup vs baseline: 5.9523x; 5.9523x over previous
//
#include <hip/hip_runtime.h>

#define NDIM 512   // D_IN == D_OUT == 512

// ---------------- histograms: deg_row[row]++, cnt_col[col]++ ----------------
__global__ __launch_bounds__(256) void hist_kernel(const int* __restrict__ ei,
                                                   int* __restrict__ deg_row,
                                                   int* __restrict__ cnt_col, int E) {
    int e = blockIdx.x * 256 + threadIdx.x;
    if (e < E) {
        atomicAdd(&deg_row[ei[e]], 1);
        atomicAdd(&cnt_col[ei[E + e]], 1);
    }
}

// ---------------- dis[i] = deg>0 ? rsqrt(deg) : 0 ----------------
__global__ __launch_bounds__(256) void rsqrt_kernel(const int* __restrict__ deg,
                                                    float* __restrict__ dis, int n) {
    int i = blockIdx.x * 256 + threadIdx.x;
    if (i < n) {
        int d = deg[i];
        dis[i] = (d > 0) ? rsqrtf((float)d) : 0.0f;
    }
}

// ---------------- single-block exclusive scan: base = exscan(cnt), base[n]=E ----------------
__global__ __launch_bounds__(256) void scan_kernel(const int* __restrict__ cnt,
                                                   int* __restrict__ base, int n) {
    __shared__ int wsum[4];
    __shared__ int carry_s;
    int tid = threadIdx.x;
    int lane = tid & 63, wid = tid >> 6;
    if (tid == 0) carry_s = 0;
    __syncthreads();
    for (int s = 0; s < n; s += 256) {
        int v = (s + tid < n) ? cnt[s + tid] : 0;
        int incl = v;
#pragma unroll
        for (int off = 1; off < 64; off <<= 1) {
            int t = __shfl_up(incl, off, 64);
            if (lane >= off) incl += t;
        }
        if (lane == 63) wsum[wid] = incl;
        __syncthreads();
        int add = 0;
#pragma unroll
        for (int w = 0; w < 4; ++w) if (w < wid) add += wsum[w];
        incl += add;
        int carry = carry_s;
        if (s + tid < n) base[s + tid] = carry + incl - v;
        int chunk_total = wsum[0] + wsum[1] + wsum[2] + wsum[3];
        __syncthreads();
        if (tid == 0) carry_s = carry + chunk_total;
        __syncthreads();
    }
    if (tid == 0) base[n] = carry_s;
}

// ---------------- fill CSR buckets with (row, norm) per edge ----------------
__global__ __launch_bounds__(256) void fill_kernel(
        const int* __restrict__ ei, const float* __restrict__ ea,
        const float* __restrict__ dis,
        const float* __restrict__ conf_w, const float* __restrict__ conf_b,
        const int* __restrict__ base, int* __restrict__ fill_cnt,
        int* __restrict__ row_sorted, float* __restrict__ norm_sorted, int E) {
    int e = blockIdx.x * 256 + threadIdx.x;
    if (e >= E) return;
    int row = ei[e];
    int col = ei[E + e];
    float w = ea[(size_t)e*3+0]*conf_w[0] + ea[(size_t)e*3+1]*conf_w[1]
            + ea[(size_t)e*3+2]*conf_w[2] + conf_b[0];
    w = 1.0f / (1.0f + __expf(-w));               // sigmoid
    float nm = dis[row] * dis[col] * w;
    int pos = base[col] + atomicAdd(&fill_cnt[col], 1);
    row_sorted[pos] = row;
    norm_sorted[pos] = nm;
}

// ---------------- gather-aggregate: agg[node] = sum over bucket x[row]*norm ----------------
// one block per destination node; thread t owns channels t and t+256
__global__ __launch_bounds__(256) void agg_kernel(
        const float* __restrict__ x, const int* __restrict__ row_sorted,
        const float* __restrict__ norm_sorted, const int* __restrict__ base,
        float* __restrict__ agg) {
    int node = blockIdx.x;
    int tid = threadIdx.x;
    int start = base[node], end = base[node + 1];
    float acc0 = 0.0f, acc1 = 0.0f;
    for (int p = start; p < end; ++p) {
        int row = row_sorted[p];
        float nm = norm_sorted[p];
        const float* __restrict__ xr = x + (size_t)row * NDIM;
        acc0 += xr[tid]       * nm;
        acc1 += xr[tid + 256] * nm;
    }
    float* __restrict__ ar = agg + (size_t)node * NDIM;
    ar[tid] = acc0;
    ar[tid + 256] = acc1;
}

// ---------------- fp32 GEMM: out[m][n] = sum_k agg[m][k]*W[n][k] + b[n] ----------------
#define BM 64
#define BN 64
#define BK 32

__global__ __launch_bounds__(256) void gemm_kernel(
        const float* __restrict__ A,   // [M][512] agg
        const float* __restrict__ W,   // [512][512] row-major [out][in]
        const float* __restrict__ bias,
        float* __restrict__ out, int M) {
    __shared__ float As[BK][BM + 4];
    __shared__ float Bs[BK][BN + 4];
    int m0 = blockIdx.x * BM;
    int n0 = blockIdx.y * BN;
    int tid = threadIdx.x;
    int tx = tid & 15, ty = tid >> 4;
    float acc[4][4] = {};

    for (int k0 = 0; k0 < NDIM; k0 += BK) {
#pragma unroll
        for (int i = 0; i < 2; ++i) {
            int idx = tid * 2 + i;          // 0..511
            int r = idx >> 3;               // 0..63
            int c = (idx & 7) * 4;          // 0..28
            float4 v = make_float4(0.f, 0.f, 0.f, 0.f);
            int gm = m0 + r;
            if (gm < M) v = *(const float4*)(A + (size_t)gm * NDIM + k0 + c);
            As[c+0][r] = v.x; As[c+1][r] = v.y; As[c+2][r] = v.z; As[c+3][r] = v.w;
            float4 u = *(const float4*)(W + (size_t)(n0 + r) * NDIM + k0 + c);
            Bs[c+0][r] = u.x; Bs[c+1][r] = u.y; Bs[c+2][r] = u.z; Bs[c+3][r] = u.w;
        }
        __syncthreads();
#pragma unroll
        for (int k = 0; k < BK; ++k) {
            float4 a4 = *(const float4*)&As[k][ty * 4];
            float4 b4 = *(const float4*)&Bs[k][tx * 4];
            float a[4] = {a4.x, a4.y, a4.z, a4.w};
            float b[4] = {b4.x, b4.y, b4.z, b4.w};
#pragma unroll
            for (int i = 0; i < 4; ++i)
#pragma unroll
                for (int j = 0; j < 4; ++j)
                    acc[i][j] += a[i] * b[j];
        }
        __syncthreads();
    }
#pragma unroll
    for (int i = 0; i < 4; ++i) {
        int gm = m0 + ty * 4 + i;
        if (gm >= M) continue;
#pragma unroll
        for (int j = 0; j < 4; ++j) {
            int gn = n0 + tx * 4 + j;
            out[(size_t)gm * NDIM + gn] = acc[i][j] + bias[gn];
        }
    }
}

extern "C" void kernel_launch(void* const* d_in, const int* in_sizes, int n_in,
                              void* d_out, int out_size, void* d_ws, size_t ws_size,
                              hipStream_t stream) {
    const float* x      = (const float*)d_in[0];
    const int*   ei     = (const int*)  d_in[1];   // edge_index [2][E]
    const float* ea     = (const float*)d_in[2];   // edge_attr [E][3]
    const float* lin_w  = (const float*)d_in[3];   // [512][512]
    const float* lin_b  = (const float*)d_in[4];   // [512]
    const float* conf_w = (const float*)d_in[5];   // [3]
    const float* conf_b = (const float*)d_in[6];   // [1]
    float* out = (float*)d_out;

    int N = in_sizes[0] / NDIM;   // 50000
    int E = in_sizes[2] / 3;      // 800000

    // ---- workspace layout (256B aligned slabs) ----
    char* p = (char*)d_ws;
    auto alloc = [&](size_t bytes) {
        char* q = p;
        p += (bytes + 255) & ~(size_t)255;
        return q;
    };
    float* agg         = (float*)alloc((size_t)N * NDIM * sizeof(float)); // 102.4 MB
    int*   deg_row     = (int*)  alloc((size_t)N * sizeof(int));          // zeroed (slab start)
    int*   cnt_col     = (int*)  alloc((size_t)N * sizeof(int));          // zeroed
    int*   fill_cnt    = (int*)  alloc((size_t)N * sizeof(int));          // zeroed (slab end)
    float* dis         = (float*)alloc((size_t)N * sizeof(float));
    int*   base        = (int*)  alloc((size_t)(N + 1) * sizeof(int));
    int*   row_sorted  = (int*)  alloc((size_t)E * sizeof(int));
    float* norm_sorted = (float*)alloc((size_t)E * sizeof(float));

    // zero the three counter arrays (contiguous slabs: deg_row..dis)
    size_t zero_bytes = (size_t)((char*)dis - (char*)deg_row);
    (void)hipMemsetAsync(deg_row, 0, zero_bytes, stream);

    int gE = (E + 255) / 256;
    int gN = (N + 255) / 256;
    hist_kernel  <<<gE, 256, 0, stream>>>(ei, deg_row, cnt_col, E);
    rsqrt_kernel <<<gN, 256, 0, stream>>>(deg_row, dis, N);
    scan_kernel  <<<1, 256, 0, stream>>>(cnt_col, base, N);
    fill_kernel  <<<gE, 256, 0, stream>>>(ei, ea, dis, conf_w, conf_b,
                                          base, fill_cnt, row_sorted, norm_sorted, E);
    agg_kernel   <<<N, 256, 0, stream>>>(x, row_sorted, norm_sorted, base, agg);
    dim3 g((N + BM - 1) / BM, NDIM / BN);
    gemm_kernel  <<<g, 256, 0, stream>>>(agg, lin_w, lin_b, out, N);
}

// Round 4
// 560.847 us; speedup vs baseline: 10.4773x; 1.7602x over previous
//
#include <hip/hip_runtime.h>

#define NDIM 512   // D_IN == D_OUT == 512

typedef __bf16 bf16x8 __attribute__((ext_vector_type(8)));
typedef float  f32x4  __attribute__((ext_vector_type(4)));

__device__ inline ushort f2bf(float f) {           // fp32 -> bf16 RNE
    uint b = __float_as_uint(f);
    return (ushort)((b + 0x7fffu + ((b >> 16) & 1u)) >> 16);
}

// ---------------- fp32 -> bf16 bulk convert (float4 -> ushort4) ----------------
__global__ __launch_bounds__(256) void f2bf_kernel(const float* __restrict__ in,
                                                   ushort* __restrict__ out, int n4) {
    int i = blockIdx.x * 256 + threadIdx.x;
    if (i >= n4) return;
    float4 v = ((const float4*)in)[i];
    ushort4 o;
    o.x = f2bf(v.x); o.y = f2bf(v.y); o.z = f2bf(v.z); o.w = f2bf(v.w);
    ((ushort4*)out)[i] = o;
}

// ---------------- histograms: deg_row[row]++, cnt_col[col]++ ----------------
__global__ __launch_bounds__(256) void hist_kernel(const int* __restrict__ ei,
                                                   int* __restrict__ deg_row,
                                                   int* __restrict__ cnt_col, int E) {
    int e = blockIdx.x * 256 + threadIdx.x;
    if (e < E) {
        atomicAdd(&deg_row[ei[e]], 1);
        atomicAdd(&cnt_col[ei[E + e]], 1);
    }
}

// ---------------- dis[i] = deg>0 ? rsqrt(deg) : 0 ----------------
__global__ __launch_bounds__(256) void rsqrt_kernel(const int* __restrict__ deg,
                                                    float* __restrict__ dis, int n) {
    int i = blockIdx.x * 256 + threadIdx.x;
    if (i < n) {
        int d = deg[i];
        dis[i] = (d > 0) ? rsqrtf((float)d) : 0.0f;
    }
}

// ------- single-block exclusive scan, 4 elems/thread: base = exscan(cnt), base[n]=E -------
__global__ __launch_bounds__(256) void scan_kernel(const int* __restrict__ cnt,
                                                   int* __restrict__ base, int n) {
    __shared__ int wsum[4];
    __shared__ int carry_s;
    int tid = threadIdx.x;
    int lane = tid & 63, wid = tid >> 6;
    if (tid == 0) carry_s = 0;
    __syncthreads();
    for (int s = 0; s < n; s += 1024) {
        int i0 = s + tid * 4;
        int v0 = (i0 + 0 < n) ? cnt[i0 + 0] : 0;
        int v1 = (i0 + 1 < n) ? cnt[i0 + 1] : 0;
        int v2 = (i0 + 2 < n) ? cnt[i0 + 2] : 0;
        int v3 = (i0 + 3 < n) ? cnt[i0 + 3] : 0;
        int tsum = v0 + v1 + v2 + v3;
        int incl = tsum;
#pragma unroll
        for (int off = 1; off < 64; off <<= 1) {
            int t = __shfl_up(incl, off, 64);
            if (lane >= off) incl += t;
        }
        if (lane == 63) wsum[wid] = incl;
        __syncthreads();                      // S1: wsum visible
        int add = carry_s;
#pragma unroll
        for (int w = 0; w < 4; ++w) if (w < wid) add += wsum[w];
        int run = add + incl - tsum;          // exclusive prefix of this thread's 4
        if (i0 + 0 < n) base[i0 + 0] = run; run += v0;
        if (i0 + 1 < n) base[i0 + 1] = run; run += v1;
        if (i0 + 2 < n) base[i0 + 2] = run; run += v2;
        if (i0 + 3 < n) base[i0 + 3] = run;
        __syncthreads();                      // S2: all reads of carry_s/wsum done
        if (tid == 255) carry_s = add + incl; // carry + chunk total
        __syncthreads();                      // S3: carry_s visible
    }
    if (tid == 0) base[n] = carry_s;
}

// ---------------- fill CSR buckets with (row, norm) per edge ----------------
__global__ __launch_bounds__(256) void fill_kernel(
        const int* __restrict__ ei, const float* __restrict__ ea,
        const float* __restrict__ dis,
        const float* __restrict__ conf_w, const float* __restrict__ conf_b,
        const int* __restrict__ base, int* __restrict__ fill_cnt,
        int* __restrict__ row_sorted, float* __restrict__ norm_sorted, int E) {
    int e = blockIdx.x * 256 + threadIdx.x;
    if (e >= E) return;
    int row = ei[e];
    int col = ei[E + e];
    float w = ea[(size_t)e*3+0]*conf_w[0] + ea[(size_t)e*3+1]*conf_w[1]
            + ea[(size_t)e*3+2]*conf_w[2] + conf_b[0];
    w = 1.0f / (1.0f + __expf(-w));               // sigmoid
    float nm = dis[row] * dis[col] * w;
    int pos = base[col] + atomicAdd(&fill_cnt[col], 1);
    row_sorted[pos] = row;
    norm_sorted[pos] = nm;
}

// ------- gather-aggregate (bf16): aggh[node] = sum over bucket xh[row]*norm -------
// one block per node; thread t owns channels 2t, 2t+1 (one packed uint load per edge)
__global__ __launch_bounds__(256) void agg_kernel(
        const ushort* __restrict__ xh, const int* __restrict__ row_sorted,
        const float* __restrict__ norm_sorted, const int* __restrict__ base,
        ushort* __restrict__ aggh) {
    int node = blockIdx.x;
    int tid = threadIdx.x;
    int start = base[node], end = base[node + 1];
    int c = tid * 2;
    float acc0 = 0.0f, acc1 = 0.0f;
    int p = start;
    for (; p + 1 < end; p += 2) {
        int r0 = row_sorted[p],       r1 = row_sorted[p + 1];
        float n0 = norm_sorted[p],    n1 = norm_sorted[p + 1];
        uint u0 = *(const uint*)(xh + (size_t)r0 * NDIM + c);
        uint u1 = *(const uint*)(xh + (size_t)r1 * NDIM + c);
        acc0 = fmaf(__uint_as_float(u0 << 16),        n0, acc0);
        acc1 = fmaf(__uint_as_float(u0 & 0xffff0000u), n0, acc1);
        acc0 = fmaf(__uint_as_float(u1 << 16),        n1, acc0);
        acc1 = fmaf(__uint_as_float(u1 & 0xffff0000u), n1, acc1);
    }
    if (p < end) {
        int r0 = row_sorted[p];
        float n0 = norm_sorted[p];
        uint u0 = *(const uint*)(xh + (size_t)r0 * NDIM + c);
        acc0 = fmaf(__uint_as_float(u0 << 16),        n0, acc0);
        acc1 = fmaf(__uint_as_float(u0 & 0xffff0000u), n0, acc1);
    }
    uint o = ((uint)f2bf(acc1) << 16) | (uint)f2bf(acc0);
    *(uint*)(aggh + (size_t)node * NDIM + c) = o;
}

// ---------------- bf16 MFMA GEMM: out[m][n] = sum_k A[m][k]*W[n][k] + bias[n] ----------------
// 128x128 tile, BK=32, 256 threads = 4 waves, each wave a 64x64 sub-tile (4x4 frags of 16x16)
__global__ __launch_bounds__(256) void mfma_gemm(
        const ushort* __restrict__ A,   // [M][512] bf16 (agg)
        const ushort* __restrict__ B,   // [512][512] bf16, row = n (out), col = k (in)
        const float* __restrict__ bias,
        float* __restrict__ out, int M) {
    // +8 pad: row stride 80B (mult of 16B -> aligned b128; 20 banks -> only free 2-way conflicts)
    __shared__ ushort As[128][40];
    __shared__ ushort Bs[128][40];
    int m0 = blockIdx.x * 128;
    int n0 = blockIdx.y * 128;
    int tid  = threadIdx.x;
    int lane = tid & 63;
    int wave = tid >> 6;
    int wr = wave >> 1, wc = wave & 1;    // wave's 64x64 origin (wr*64, wc*64)
    int quad = lane >> 4, l16 = lane & 15;

    f32x4 acc[4][4] = {};                  // [mt][nt]

    for (int k0 = 0; k0 < NDIM; k0 += 32) {
        // stage 128 rows x 32 k of A and B: 512 x 16B chunks each, 2 per thread
#pragma unroll
        for (int i = 0; i < 2; ++i) {
            int idx = tid + i * 256;       // 0..511
            int r  = idx >> 2;             // 0..127
            int ck = (idx & 3) * 8;        // 0,8,16,24
            uint4 av = make_uint4(0u, 0u, 0u, 0u);
            int gm = m0 + r;
            if (gm < M) av = *(const uint4*)(A + (size_t)gm * NDIM + k0 + ck);
            *(uint4*)&As[r][ck] = av;
            *(uint4*)&Bs[r][ck] = *(const uint4*)(B + (size_t)(n0 + r) * NDIM + k0 + ck);
        }
        __syncthreads();
#pragma unroll
        for (int mt = 0; mt < 4; ++mt) {
            bf16x8 a = *(const bf16x8*)&As[wr * 64 + mt * 16 + l16][quad * 8];
#pragma unroll
            for (int nt = 0; nt < 4; ++nt) {
                bf16x8 b = *(const bf16x8*)&Bs[wc * 64 + nt * 16 + l16][quad * 8];
                acc[mt][nt] = __builtin_amdgcn_mfma_f32_16x16x32_bf16(a, b, acc[mt][nt], 0, 0, 0);
            }
        }
        __syncthreads();
    }
    // epilogue: C/D layout col = lane&15, row = quad*4 + reg
#pragma unroll
    for (int mt = 0; mt < 4; ++mt) {
#pragma unroll
        for (int nt = 0; nt < 4; ++nt) {
            int gn = n0 + wc * 64 + nt * 16 + l16;
            float bv = bias[gn];
#pragma unroll
            for (int r = 0; r < 4; ++r) {
                int gm = m0 + wr * 64 + mt * 16 + quad * 4 + r;
                if (gm < M) out[(size_t)gm * NDIM + gn] = acc[mt][nt][r] + bv;
            }
        }
    }
}

extern "C" void kernel_launch(void* const* d_in, const int* in_sizes, int n_in,
                              void* d_out, int out_size, void* d_ws, size_t ws_size,
                              hipStream_t stream) {
    const float* x      = (const float*)d_in[0];
    const int*   ei     = (const int*)  d_in[1];   // edge_index [2][E]
    const float* ea     = (const float*)d_in[2];   // edge_attr [E][3]
    const float* lin_w  = (const float*)d_in[3];   // [512][512]
    const float* lin_b  = (const float*)d_in[4];   // [512]
    const float* conf_w = (const float*)d_in[5];   // [3]
    const float* conf_b = (const float*)d_in[6];   // [1]
    float* out = (float*)d_out;

    int N = in_sizes[0] / NDIM;   // 50000
    int E = in_sizes[2] / 3;      // 800000

    // ---- workspace layout (256B aligned slabs) ----
    char* p = (char*)d_ws;
    auto alloc = [&](size_t bytes) {
        char* q = p;
        p += (bytes + 255) & ~(size_t)255;
        return q;
    };
    ushort* aggh       = (ushort*)alloc((size_t)N * NDIM * sizeof(ushort)); // 51.2 MB
    ushort* wh         = (ushort*)alloc((size_t)NDIM * NDIM * sizeof(ushort));
    int*   deg_row     = (int*)  alloc((size_t)N * sizeof(int));            // zeroed slab start
    int*   cnt_col     = (int*)  alloc((size_t)N * sizeof(int));            // zeroed
    int*   fill_cnt    = (int*)  alloc((size_t)N * sizeof(int));            // zeroed slab end
    float* dis         = (float*)alloc((size_t)N * sizeof(float));
    int*   base        = (int*)  alloc((size_t)(N + 1) * sizeof(int));
    int*   row_sorted  = (int*)  alloc((size_t)E * sizeof(int));
    float* norm_sorted = (float*)alloc((size_t)E * sizeof(float));

    // xh (bf16 x, 51.2 MB) lives in the d_out buffer (102.4 MB): consumed by agg_kernel,
    // which completes (stream order) before mfma_gemm writes out.
    ushort* xh = (ushort*)d_out;

    size_t zero_bytes = (size_t)((char*)dis - (char*)deg_row);
    (void)hipMemsetAsync(deg_row, 0, zero_bytes, stream);

    int gE = (E + 255) / 256;
    int gN = (N + 255) / 256;
    int x4 = (N * NDIM) / 4, w4 = (NDIM * NDIM) / 4;
    f2bf_kernel  <<<(x4 + 255) / 256, 256, 0, stream>>>(x, xh, x4);
    f2bf_kernel  <<<(w4 + 255) / 256, 256, 0, stream>>>(lin_w, wh, w4);
    hist_kernel  <<<gE, 256, 0, stream>>>(ei, deg_row, cnt_col, E);
    rsqrt_kernel <<<gN, 256, 0, stream>>>(deg_row, dis, N);
    scan_kernel  <<<1, 256, 0, stream>>>(cnt_col, base, N);
    fill_kernel  <<<gE, 256, 0, stream>>>(ei, ea, dis, conf_w, conf_b,
                                          base, fill_cnt, row_sorted, norm_sorted, E);
    agg_kernel   <<<N, 256, 0, stream>>>(xh, row_sorted, norm_sorted, base, aggh);
    dim3 g((N + 127) / 128, NDIM / 128);
    mfma_gemm    <<<g, 256, 0, stream>>>(aggh, wh, lin_b, out, N);
}

// Round 5
// 559.329 us; speedup vs baseline: 10.5057x; 1.0027x over previous
//
#include <hip/hip_runtime.h>

#define NDIM 512   // D_IN == D_OUT == 512

typedef __bf16 bf16x8 __attribute__((ext_vector_type(8)));
typedef float  f32x4  __attribute__((ext_vector_type(4)));

__device__ inline ushort f2bf(float f) {           // fp32 -> bf16 RNE
    uint b = __float_as_uint(f);
    return (ushort)((b + 0x7fffu + ((b >> 16) & 1u)) >> 16);
}
__device__ inline float bflo(uint u) { return __uint_as_float(u << 16); }
__device__ inline float bfhi(uint u) { return __uint_as_float(u & 0xffff0000u); }

// async global->LDS, 16B per lane; lds base must be wave-uniform (dest = base + lane*16)
__device__ inline void gload16(const ushort* g, ushort* l) {
    __builtin_amdgcn_global_load_lds(
        (const __attribute__((address_space(1))) uint*)g,
        (__attribute__((address_space(3))) uint*)l, 16, 0, 0);
}

// ---------------- fp32 -> bf16 bulk convert (float4 -> ushort4) ----------------
__global__ __launch_bounds__(256) void f2bf_kernel(const float* __restrict__ in,
                                                   ushort* __restrict__ out, int n4) {
    int i = blockIdx.x * 256 + threadIdx.x;
    if (i >= n4) return;
    float4 v = ((const float4*)in)[i];
    ushort4 o;
    o.x = f2bf(v.x); o.y = f2bf(v.y); o.z = f2bf(v.z); o.w = f2bf(v.w);
    ((ushort4*)out)[i] = o;
}

// ---------------- histograms: deg_row[row]++, cnt_col[col]++ ----------------
__global__ __launch_bounds__(256) void hist_kernel(const int* __restrict__ ei,
                                                   int* __restrict__ deg_row,
                                                   int* __restrict__ cnt_col, int E) {
    int e = blockIdx.x * 256 + threadIdx.x;
    if (e < E) {
        atomicAdd(&deg_row[ei[e]], 1);
        atomicAdd(&cnt_col[ei[E + e]], 1);
    }
}

// ---------------- dis[i] = deg>0 ? rsqrt(deg) : 0 ----------------
__global__ __launch_bounds__(256) void rsqrt_kernel(const int* __restrict__ deg,
                                                    float* __restrict__ dis, int n) {
    int i = blockIdx.x * 256 + threadIdx.x;
    if (i < n) {
        int d = deg[i];
        dis[i] = (d > 0) ? rsqrtf((float)d) : 0.0f;
    }
}

// ------- single-block exclusive scan, 1024 thr x int4: base = exscan(cnt), base[n]=E -------
__global__ __launch_bounds__(1024) void scan_kernel(const int* __restrict__ cnt,
                                                    int* __restrict__ base, int n) {
    __shared__ int wsum[16];
    __shared__ int carry_s;
    int tid = threadIdx.x;
    int lane = tid & 63, wid = tid >> 6;
    if (tid == 0) carry_s = 0;
    __syncthreads();
    for (int s = 0; s < n; s += 4096) {
        int i0 = s + tid * 4;
        int v0 = 0, v1 = 0, v2 = 0, v3 = 0;
        if (i0 + 3 < n) {
            int4 q = *(const int4*)(cnt + i0);
            v0 = q.x; v1 = q.y; v2 = q.z; v3 = q.w;
        } else if (i0 < n) {
            v0 = cnt[i0];
            if (i0 + 1 < n) v1 = cnt[i0 + 1];
            if (i0 + 2 < n) v2 = cnt[i0 + 2];
        }
        int tsum = v0 + v1 + v2 + v3;
        int incl = tsum;
#pragma unroll
        for (int off = 1; off < 64; off <<= 1) {
            int t = __shfl_up(incl, off, 64);
            if (lane >= off) incl += t;
        }
        if (lane == 63) wsum[wid] = incl;
        __syncthreads();                      // wsum visible
        int add = carry_s;
#pragma unroll
        for (int w = 0; w < 16; ++w) if (w < wid) add += wsum[w];
        int run = add + incl - tsum;          // exclusive prefix of this thread's 4
        if (i0 + 0 < n) base[i0 + 0] = run; run += v0;
        if (i0 + 1 < n) base[i0 + 1] = run; run += v1;
        if (i0 + 2 < n) base[i0 + 2] = run; run += v2;
        if (i0 + 3 < n) base[i0 + 3] = run;
        __syncthreads();                      // all reads of carry_s/wsum done
        if (tid == 1023) carry_s = add + incl;
        __syncthreads();                      // carry_s visible
    }
    if (tid == 0) base[n] = carry_s;
}

// ---------------- fill CSR buckets with (row, norm) per edge ----------------
__global__ __launch_bounds__(256) void fill_kernel(
        const int* __restrict__ ei, const float* __restrict__ ea,
        const float* __restrict__ dis,
        const float* __restrict__ conf_w, const float* __restrict__ conf_b,
        const int* __restrict__ base, int* __restrict__ fill_cnt,
        int* __restrict__ row_sorted, float* __restrict__ norm_sorted, int E) {
    int e = blockIdx.x * 256 + threadIdx.x;
    if (e >= E) return;
    int row = ei[e];
    int col = ei[E + e];
    float w = ea[(size_t)e*3+0]*conf_w[0] + ea[(size_t)e*3+1]*conf_w[1]
            + ea[(size_t)e*3+2]*conf_w[2] + conf_b[0];
    w = 1.0f / (1.0f + __expf(-w));               // sigmoid
    float nm = dis[row] * dis[col] * w;
    int pos = base[col] + atomicAdd(&fill_cnt[col], 1);
    row_sorted[pos] = row;
    norm_sorted[pos] = nm;
}

// ------- gather-aggregate (bf16): aggh[node] = sum over bucket xh[row]*norm -------
// one block per node; two half-blocks of 128 threads each take alternate edges;
// thread t of a half owns channels 4t..4t+3 (one uint2 = 8B load per edge)
__global__ __launch_bounds__(256) void agg_kernel(
        const ushort* __restrict__ xh, const int* __restrict__ row_sorted,
        const float* __restrict__ norm_sorted, const int* __restrict__ base,
        ushort* __restrict__ aggh) {
    __shared__ float4 red[128];
    int node = blockIdx.x;
    int tid = threadIdx.x;
    int half = tid >> 7;
    int t = tid & 127;
    int c = t * 4;
    int start = base[node], end = base[node + 1];
    float a0 = 0.f, a1 = 0.f, a2 = 0.f, a3 = 0.f;
    for (int p = start + half; p < end; p += 2) {
        int r = row_sorted[p];
        float nm = norm_sorted[p];
        uint2 u = *(const uint2*)(xh + (size_t)r * NDIM + c);
        a0 = fmaf(bflo(u.x), nm, a0);
        a1 = fmaf(bfhi(u.x), nm, a1);
        a2 = fmaf(bflo(u.y), nm, a2);
        a3 = fmaf(bfhi(u.y), nm, a3);
    }
    if (half) red[t] = make_float4(a0, a1, a2, a3);
    __syncthreads();
    if (!half) {
        float4 r = red[t];
        a0 += r.x; a1 += r.y; a2 += r.z; a3 += r.w;
        uint2 o;
        o.x = ((uint)f2bf(a1) << 16) | (uint)f2bf(a0);
        o.y = ((uint)f2bf(a3) << 16) | (uint)f2bf(a2);
        *(uint2*)(aggh + (size_t)node * NDIM + c) = o;
    }
}

// ---------------- bf16 MFMA GEMM (m97 structure): out = A @ B^T + bias ----------------
// 128x128 tile, BK=32, 256 threads = 4 waves, global_load_lds 16B staging,
// unpadded LDS [128][32] bf16 (64B rows) — the verified m97 layout
__global__ __launch_bounds__(256) void mfma_gemm(
        const ushort* __restrict__ A,   // [M][512] bf16 (agg)
        const ushort* __restrict__ B,   // [512][512] bf16, row = n (out), col = k (in)
        const float* __restrict__ bias,
        float* __restrict__ out, int M) {
    __shared__ ushort As[128 * 32];     // 8 KB
    __shared__ ushort Bs[128 * 32];     // 8 KB
    int m0 = blockIdx.x * 128;
    int n0 = blockIdx.y * 128;
    int tid  = threadIdx.x;
    int lane = tid & 63;
    int wave = tid >> 6;
    int wr = wave >> 1, wc = wave & 1;    // wave's 64x64 origin (wr*64, wc*64)
    int quad = lane >> 4, l16 = lane & 15;
    int lrow = lane >> 2, lcol = (lane & 3) << 3;   // staging: row-in-chunk, k-offset

    f32x4 acc[4][4] = {};                  // [mt][nt]

    for (int k0 = 0; k0 < NDIM; k0 += 32) {
        // stage A,B tiles: 8 chunks each of 16 rows x 32 k (1 KB); wave w does chunks 2w,2w+1
#pragma unroll
        for (int i = 0; i < 2; ++i) {
            int ch = wave * 2 + i;          // 0..7
            int r  = ch * 16 + lrow;        // 0..127
            int gm = m0 + r; if (gm >= M) gm = M - 1;   // clamp: junk rows never stored
            gload16(A + ((size_t)gm << 9) + k0 + lcol, &As[ch * 512]);
            gload16(B + ((size_t)(n0 + r) << 9) + k0 + lcol, &Bs[ch * 512]);
        }
        __syncthreads();
#pragma unroll
        for (int mt = 0; mt < 4; ++mt) {
            bf16x8 a = *(const bf16x8*)&As[(wr * 64 + mt * 16 + l16) * 32 + quad * 8];
#pragma unroll
            for (int nt = 0; nt < 4; ++nt) {
                bf16x8 b = *(const bf16x8*)&Bs[(wc * 64 + nt * 16 + l16) * 32 + quad * 8];
                acc[mt][nt] = __builtin_amdgcn_mfma_f32_16x16x32_bf16(a, b, acc[mt][nt], 0, 0, 0);
            }
        }
        __syncthreads();
    }
    // epilogue: C/D layout col = lane&15, row = quad*4 + reg
#pragma unroll
    for (int mt = 0; mt < 4; ++mt) {
#pragma unroll
        for (int nt = 0; nt < 4; ++nt) {
            int gn = n0 + wc * 64 + nt * 16 + l16;
            float bv = bias[gn];
#pragma unroll
            for (int r = 0; r < 4; ++r) {
                int gm = m0 + wr * 64 + mt * 16 + quad * 4 + r;
                if (gm < M) out[(size_t)gm * NDIM + gn] = acc[mt][nt][r] + bv;
            }
        }
    }
}

extern "C" void kernel_launch(void* const* d_in, const int* in_sizes, int n_in,
                              void* d_out, int out_size, void* d_ws, size_t ws_size,
                              hipStream_t stream) {
    const float* x      = (const float*)d_in[0];
    const int*   ei     = (const int*)  d_in[1];   // edge_index [2][E]
    const float* ea     = (const float*)d_in[2];   // edge_attr [E][3]
    const float* lin_w  = (const float*)d_in[3];   // [512][512]
    const float* lin_b  = (const float*)d_in[4];   // [512]
    const float* conf_w = (const float*)d_in[5];   // [3]
    const float* conf_b = (const float*)d_in[6];   // [1]
    float* out = (float*)d_out;

    int N = in_sizes[0] / NDIM;   // 50000
    int E = in_sizes[2] / 3;      // 800000

    // ---- workspace layout (256B aligned slabs) ----
    char* p = (char*)d_ws;
    auto alloc = [&](size_t bytes) {
        char* q = p;
        p += (bytes + 255) & ~(size_t)255;
        return q;
    };
    ushort* aggh       = (ushort*)alloc((size_t)N * NDIM * sizeof(ushort)); // 51.2 MB
    ushort* wh         = (ushort*)alloc((size_t)NDIM * NDIM * sizeof(ushort));
    int*   deg_row     = (int*)  alloc((size_t)N * sizeof(int));            // zeroed slab start
    int*   cnt_col     = (int*)  alloc((size_t)N * sizeof(int));            // zeroed
    int*   fill_cnt    = (int*)  alloc((size_t)N * sizeof(int));            // zeroed slab end
    float* dis         = (float*)alloc((size_t)N * sizeof(float));
    int*   base        = (int*)  alloc((size_t)(N + 1) * sizeof(int));
    int*   row_sorted  = (int*)  alloc((size_t)E * sizeof(int));
    float* norm_sorted = (float*)alloc((size_t)E * sizeof(float));

    // xh (bf16 x, 51.2 MB) lives in the d_out buffer (102.4 MB): consumed by agg_kernel,
    // which completes (stream order) before mfma_gemm writes out.
    ushort* xh = (ushort*)d_out;

    size_t zero_bytes = (size_t)((char*)dis - (char*)deg_row);
    (void)hipMemsetAsync(deg_row, 0, zero_bytes, stream);

    int gE = (E + 255) / 256;
    int gN = (N + 255) / 256;
    int x4 = (N * NDIM) / 4, w4 = (NDIM * NDIM) / 4;
    f2bf_kernel  <<<(x4 + 255) / 256, 256, 0, stream>>>(x, xh, x4);
    f2bf_kernel  <<<(w4 + 255) / 256, 256, 0, stream>>>(lin_w, wh, w4);
    hist_kernel  <<<gE, 256, 0, stream>>>(ei, deg_row, cnt_col, E);
    rsqrt_kernel <<<gN, 256, 0, stream>>>(deg_row, dis, N);
    scan_kernel  <<<1, 1024, 0, stream>>>(cnt_col, base, N);
    fill_kernel  <<<gE, 256, 0, stream>>>(ei, ea, dis, conf_w, conf_b,
                                          base, fill_cnt, row_sorted, norm_sorted, E);
    agg_kernel   <<<N, 256, 0, stream>>>(xh, row_sorted, norm_sorted, base, aggh);
    dim3 g((N + 127) / 128, NDIM / 128);
    mfma_gemm    <<<g, 256, 0, stream>>>(aggh, wh, lin_b, out, N);
}